// Round 1
// baseline (163.126 us; speedup 1.0000x reference)
//
#include <hip/hip_runtime.h>

#define BATCH 8
#define NPTS 4096
#define KSEL 6          // K_NN + 1
#define ALPHA 1.05f
#define NSEG 8          // candidate-scan split per point

// ---------------------------------------------------------------------------
// Kernel 1: per-point mean 5-NN squared distance.
// grid = BATCH * (NPTS/64) = 512 blocks, block = 512 threads (8 waves).
// Wave w (seg = tid>>6) scans candidate segment [seg*512, seg*512+512) for all
// 64 points of the block; seg is wave-uniform -> candidate loads are scalar
// (s_load) since address depends only on (blockIdx, seg, loop var).
// ---------------------------------------------------------------------------
__global__ __launch_bounds__(512) void knn_value_kernel(const float* __restrict__ pc,
                                                        float* __restrict__ value) {
  __shared__ float cand[NSEG][64][KSEL];

  const int tid = threadIdx.x;
  const int pt  = tid & 63;
  const int seg = __builtin_amdgcn_readfirstlane(tid >> 6);  // wave-uniform
  const int b    = blockIdx.x >> 6;
  const int tile = blockIdx.x & 63;
  const int i    = tile * 64 + pt;

  const float* __restrict__ base = pc + (size_t)b * (NPTS * 3);
  const float xi = base[i * 3 + 0];
  const float yi = base[i * 3 + 1];
  const float zi = base[i * 3 + 2];

  float m[KSEL];
#pragma unroll
  for (int k = 0; k < KSEL; ++k) m[k] = 3.4e38f;

  const int j0 = seg * (NPTS / NSEG);
#pragma unroll 4
  for (int jj = 0; jj < NPTS / NSEG; ++jj) {
    const int j = j0 + jj;
    const float cx = base[j * 3 + 0];   // wave-uniform -> scalar load
    const float cy = base[j * 3 + 1];
    const float cz = base[j * 3 + 2];
    const float dx = xi - cx;
    const float dy = yi - cy;
    const float dz = zi - cz;
    const float d  = dx * dx + dy * dy + dz * dz;  // j==i gives exactly 0
    if (d < m[KSEL - 1]) {
      m[KSEL - 1] = d;
#pragma unroll
      for (int k = KSEL - 1; k > 0; --k) {   // one bubble pass re-sorts
        const float lo = fminf(m[k - 1], m[k]);
        const float hi = fmaxf(m[k - 1], m[k]);
        m[k - 1] = lo;
        m[k]     = hi;
      }
    }
  }

#pragma unroll
  for (int k = 0; k < KSEL; ++k) cand[seg][pt][k] = m[k];
  __syncthreads();

  // One thread per point merges the NSEG partial top-6 lists.
  if (tid < 64) {
    float mm[KSEL];
#pragma unroll
    for (int k = 0; k < KSEL; ++k) mm[k] = 3.4e38f;
    for (int s = 0; s < NSEG; ++s) {
#pragma unroll
      for (int k = 0; k < KSEL; ++k) {
        const float d = cand[s][tid][k];
        if (d < mm[KSEL - 1]) {
          mm[KSEL - 1] = d;
#pragma unroll
          for (int q = KSEL - 1; q > 0; --q) {
            const float lo = fminf(mm[q - 1], mm[q]);
            const float hi = fmaxf(mm[q - 1], mm[q]);
            mm[q - 1] = lo;
            mm[q]     = hi;
          }
        }
      }
    }
    // drop the smallest (self-distance 0), mean of remaining 5
    float s5 = 0.f;
#pragma unroll
    for (int k = 1; k < KSEL; ++k) s5 += mm[k];
    value[b * NPTS + tile * 64 + tid] = s5 * 0.2f;
  }
}

// ---------------------------------------------------------------------------
// Kernel 2: per-batch mean / unbiased std / threshold / masked mean * weight.
// grid = 8 blocks, block = 256 threads, three reduction passes.
// ---------------------------------------------------------------------------
__global__ __launch_bounds__(256) void stats_kernel(const float* __restrict__ value,
                                                    const float* __restrict__ weights,
                                                    float* __restrict__ loss_b) {
  __shared__ float red[256];
  const int b   = blockIdx.x;
  const int tid = threadIdx.x;
  const float* __restrict__ v = value + b * NPTS;

  // pass 1: mean
  float s = 0.f;
  for (int j = tid; j < NPTS; j += 256) s += v[j];
  red[tid] = s;
  __syncthreads();
  for (int off = 128; off > 0; off >>= 1) {
    if (tid < off) red[tid] += red[tid + off];
    __syncthreads();
  }
  const float mean = red[0] * (1.0f / NPTS);
  __syncthreads();

  // pass 2: unbiased std
  float s2 = 0.f;
  for (int j = tid; j < NPTS; j += 256) {
    const float d = v[j] - mean;
    s2 += d * d;
  }
  red[tid] = s2;
  __syncthreads();
  for (int off = 128; off > 0; off >>= 1) {
    if (tid < off) red[tid] += red[tid + off];
    __syncthreads();
  }
  const float thr = mean + ALPHA * sqrtf(red[0] * (1.0f / (NPTS - 1)));
  __syncthreads();

  // pass 3: masked sum (strict >)
  float s3 = 0.f;
  for (int j = tid; j < NPTS; j += 256) {
    const float vv = v[j];
    if (vv > thr) s3 += vv;
  }
  red[tid] = s3;
  __syncthreads();
  for (int off = 128; off > 0; off >>= 1) {
    if (tid < off) red[tid] += red[tid + off];
    __syncthreads();
  }
  if (tid == 0) loss_b[b] = red[0] * (1.0f / NPTS) * weights[b];
}

// ---------------------------------------------------------------------------
// Kernel 3: final mean over batches.
// ---------------------------------------------------------------------------
__global__ void final_kernel(const float* __restrict__ loss_b, float* __restrict__ out) {
  if (threadIdx.x == 0) {
    float s = 0.f;
    for (int b = 0; b < BATCH; ++b) s += loss_b[b];
    out[0] = s * (1.0f / BATCH);
  }
}

extern "C" void kernel_launch(void* const* d_in, const int* in_sizes, int n_in,
                              void* d_out, int out_size, void* d_ws, size_t ws_size,
                              hipStream_t stream) {
  const float* pc      = (const float*)d_in[0];   // [8,4096,3] f32
  const float* weights = (const float*)d_in[1];   // [8] f32
  float* out   = (float*)d_out;                   // scalar f32
  float* value = (float*)d_ws;                    // [8*4096] f32
  float* lossb = value + BATCH * NPTS;            // [8] f32

  knn_value_kernel<<<dim3(BATCH * (NPTS / 64)), dim3(512), 0, stream>>>(pc, value);
  stats_kernel<<<dim3(BATCH), dim3(256), 0, stream>>>(value, weights, lossb);
  final_kernel<<<dim3(1), dim3(64), 0, stream>>>(lossb, out);
}

// Round 2
// 119.555 us; speedup vs baseline: 1.3644x; 1.3644x over previous
//
#include <hip/hip_runtime.h>

#define BATCH 8
#define NPTS 4096
#define KSEL 6          // K_NN + 1
#define ALPHA 1.05f
#define NSEG 8          // candidate-scan split per point

// ---------------------------------------------------------------------------
// Kernel 1: per-point mean 5-NN squared distance.
// grid = BATCH * (NPTS/64) = 512 blocks, block = 512 threads (8 waves).
// Wave w (seg = tid>>6) scans candidate segment [seg*512, (seg+1)*512) for all
// 64 points of the block; seg is wave-uniform -> candidate loads are scalar.
// Selection: BRANCHLESS sorted-insert (11 min/max ops) — no divergence, no
// exec-mask churn; 2 candidates per iteration for ILP across the two serial
// min/max chains.
// ---------------------------------------------------------------------------
__global__ __launch_bounds__(512) void knn_value_kernel(const float* __restrict__ pc,
                                                        float* __restrict__ value,
                                                        float* __restrict__ out) {
  __shared__ float cand[NSEG][64][KSEL];

  const int tid = threadIdx.x;
  const int pt  = tid & 63;
  const int seg = __builtin_amdgcn_readfirstlane(tid >> 6);  // wave-uniform
  const int b    = blockIdx.x >> 6;
  const int tile = blockIdx.x & 63;
  const int i    = tile * 64 + pt;

  if (blockIdx.x == 0 && tid == 0) out[0] = 0.0f;  // stats kernel accumulates

  const float* __restrict__ base = pc + (size_t)b * (NPTS * 3);
  const float xi = base[i * 3 + 0];
  const float yi = base[i * 3 + 1];
  const float zi = base[i * 3 + 2];

  float m[KSEL];
#pragma unroll
  for (int k = 0; k < KSEL; ++k) m[k] = 3.4e38f;

  const float* __restrict__ cbase = base + seg * (NPTS / NSEG) * 3;
#pragma unroll 4
  for (int jj = 0; jj < NPTS / NSEG; jj += 2) {
    // two wave-uniform candidates -> scalar loads
    const float cxA = cbase[jj * 3 + 0];
    const float cyA = cbase[jj * 3 + 1];
    const float czA = cbase[jj * 3 + 2];
    const float cxB = cbase[jj * 3 + 3];
    const float cyB = cbase[jj * 3 + 4];
    const float czB = cbase[jj * 3 + 5];

    const float dxA = xi - cxA, dyA = yi - cyA, dzA = zi - czA;
    const float dxB = xi - cxB, dyB = yi - cyB, dzB = zi - czB;
    float dA = dxA * dxA;
    float dB = dxB * dxB;
    dA = fmaf(dyA, dyA, dA);
    dB = fmaf(dyB, dyB, dB);
    dA = fmaf(dzA, dzA, dA);
    dB = fmaf(dzB, dzB, dB);

    // branchless sorted insert, two independent chains
    float tA = dA, tB = dB;
#pragma unroll
    for (int k = 0; k < KSEL - 1; ++k) {
      const float loA = fminf(m[k], tA);
      tA = fmaxf(m[k], tA);
      const float loB = fminf(loA, tB);
      tB = fmaxf(loA, tB);
      m[k] = loB;
    }
    m[KSEL - 1] = fminf(fminf(m[KSEL - 1], tA), tB);
  }

  // NOTE: interleaving A then B through the same m[k] as above is equivalent
  // to inserting A then inserting B (each level: the two smallest of
  // {m[k], tA, tB} ... ) -- wait, it must keep BOTH survivors. See proof:
  // inserting A fully then B fully touches m[k] twice per level; fusing per
  // level as done here performs: m[k] <- min3(m,tA,tB) and propagates the two
  // larger values. min3 == loB above; propagated are max(m,tA) and
  // max(min(m,tA),tB) == the two larger of the triple. Correct.

#pragma unroll
  for (int k = 0; k < KSEL; ++k) cand[seg][pt][k] = m[k];
  __syncthreads();

  // One thread per point merges the NSEG sorted partial lists (branchless).
  if (tid < 64) {
    float mm[KSEL];
#pragma unroll
    for (int k = 0; k < KSEL; ++k) mm[k] = cand[0][tid][k];
    for (int s = 1; s < NSEG; ++s) {
#pragma unroll
      for (int k = 0; k < KSEL; ++k) {
        float t = cand[s][tid][k];
#pragma unroll
        for (int q = 0; q < KSEL - 1; ++q) {
          const float lo = fminf(mm[q], t);
          t = fmaxf(mm[q], t);
          mm[q] = lo;
        }
        mm[KSEL - 1] = fminf(mm[KSEL - 1], t);
      }
    }
    // drop the smallest (self-distance 0), mean of remaining 5
    float s5 = 0.f;
#pragma unroll
    for (int k = 1; k < KSEL; ++k) s5 += mm[k];
    value[b * NPTS + tile * 64 + tid] = s5 * 0.2f;
  }
}

// ---------------------------------------------------------------------------
// Kernel 2: per-batch mean / unbiased std / threshold / masked mean * weight,
// then atomicAdd of loss*(1/BATCH) into out (zeroed by kernel 1).
// grid = 8 blocks, block = 256 threads.
// ---------------------------------------------------------------------------
__global__ __launch_bounds__(256) void stats_kernel(const float* __restrict__ value,
                                                    const float* __restrict__ weights,
                                                    float* __restrict__ out) {
  __shared__ float red[256];
  const int b   = blockIdx.x;
  const int tid = threadIdx.x;
  const float* __restrict__ v = value + b * NPTS;

  // pass 1: mean
  float s = 0.f;
  for (int j = tid; j < NPTS; j += 256) s += v[j];
  red[tid] = s;
  __syncthreads();
  for (int off = 128; off > 0; off >>= 1) {
    if (tid < off) red[tid] += red[tid + off];
    __syncthreads();
  }
  const float mean = red[0] * (1.0f / NPTS);
  __syncthreads();

  // pass 2: unbiased std
  float s2 = 0.f;
  for (int j = tid; j < NPTS; j += 256) {
    const float d = v[j] - mean;
    s2 += d * d;
  }
  red[tid] = s2;
  __syncthreads();
  for (int off = 128; off > 0; off >>= 1) {
    if (tid < off) red[tid] += red[tid + off];
    __syncthreads();
  }
  const float thr = mean + ALPHA * sqrtf(red[0] * (1.0f / (NPTS - 1)));
  __syncthreads();

  // pass 3: masked sum (strict >)
  float s3 = 0.f;
  for (int j = tid; j < NPTS; j += 256) {
    const float vv = v[j];
    if (vv > thr) s3 += vv;
  }
  red[tid] = s3;
  __syncthreads();
  for (int off = 128; off > 0; off >>= 1) {
    if (tid < off) red[tid] += red[tid + off];
    __syncthreads();
  }
  if (tid == 0) {
    atomicAdd(out, red[0] * (1.0f / NPTS) * weights[b] * (1.0f / BATCH));
  }
}

extern "C" void kernel_launch(void* const* d_in, const int* in_sizes, int n_in,
                              void* d_out, int out_size, void* d_ws, size_t ws_size,
                              hipStream_t stream) {
  const float* pc      = (const float*)d_in[0];   // [8,4096,3] f32
  const float* weights = (const float*)d_in[1];   // [8] f32
  float* out   = (float*)d_out;                   // scalar f32
  float* value = (float*)d_ws;                    // [8*4096] f32

  knn_value_kernel<<<dim3(BATCH * (NPTS / 64)), dim3(512), 0, stream>>>(pc, value, out);
  stats_kernel<<<dim3(BATCH), dim3(256), 0, stream>>>(value, weights, out);
}

// Round 3
// 115.371 us; speedup vs baseline: 1.4139x; 1.0363x over previous
//
#include <hip/hip_runtime.h>

#define BATCH 8
#define NPTS 4096
#define KSEL 6          // K_NN + 1
#define ALPHA 1.05f
#define NSEG 8          // candidate-scan split per point

// Non-negative IEEE floats order identically to their uint bit patterns.
// uint min/max avoid the IEEE-mode NaN-canonicalization (v_max_f32 v,v,v)
// that fminf/fmaxf incur -> exactly one v_min_u32/v_max_u32 each.
static __device__ __forceinline__ unsigned umn(unsigned a, unsigned b) { return a < b ? a : b; }
static __device__ __forceinline__ unsigned umx(unsigned a, unsigned b) { return a > b ? a : b; }

#define FINF 0x7F800000u   // +inf bit pattern

// ---------------------------------------------------------------------------
// Kernel 1: per-point mean 5-NN squared distance.
// grid = BATCH * (NPTS/64) = 512 blocks, block = 512 threads (8 waves).
// Wave w (seg = tid>>6) scans candidate segment [seg*512, (seg+1)*512) for all
// 64 points of the block; seg is wave-uniform -> candidate loads are scalar.
// Selection: branchless sorted-insert on uint bit patterns, 2 candidates per
// iteration for ILP across the two min/max chains.
// ---------------------------------------------------------------------------
__global__ __launch_bounds__(512) void knn_value_kernel(const float* __restrict__ pc,
                                                        float* __restrict__ value,
                                                        float* __restrict__ out) {
  __shared__ unsigned cand[NSEG][64][KSEL];

  const int tid = threadIdx.x;
  const int pt  = tid & 63;
  const int seg = __builtin_amdgcn_readfirstlane(tid >> 6);  // wave-uniform
  const int b    = blockIdx.x >> 6;
  const int tile = blockIdx.x & 63;
  const int i    = tile * 64 + pt;

  if (blockIdx.x == 0 && tid == 0) out[0] = 0.0f;  // stats kernel accumulates

  const float* __restrict__ base = pc + (size_t)b * (NPTS * 3);
  const float xi = base[i * 3 + 0];
  const float yi = base[i * 3 + 1];
  const float zi = base[i * 3 + 2];

  unsigned m[KSEL];
#pragma unroll
  for (int k = 0; k < KSEL; ++k) m[k] = FINF;

  const float* __restrict__ cbase = base + seg * (NPTS / NSEG) * 3;
#pragma unroll 4
  for (int jj = 0; jj < NPTS / NSEG; jj += 2) {
    // two wave-uniform candidates -> scalar loads
    const float cxA = cbase[jj * 3 + 0];
    const float cyA = cbase[jj * 3 + 1];
    const float czA = cbase[jj * 3 + 2];
    const float cxB = cbase[jj * 3 + 3];
    const float cyB = cbase[jj * 3 + 4];
    const float czB = cbase[jj * 3 + 5];

    const float dxA = xi - cxA, dyA = yi - cyA, dzA = zi - czA;
    const float dxB = xi - cxB, dyB = yi - cyB, dzB = zi - czB;
    float dA = dxA * dxA;
    float dB = dxB * dxB;
    dA = fmaf(dyA, dyA, dA);
    dB = fmaf(dyB, dyB, dB);
    dA = fmaf(dzA, dzA, dA);
    dB = fmaf(dzB, dzB, dB);

    // branchless fused insert of {dA,dB}: per level keep min3(m,tA,tB),
    // propagate the two larger survivors. (Verified: absmax 0.0 in R2.)
    unsigned tA = __float_as_uint(dA);
    unsigned tB = __float_as_uint(dB);
#pragma unroll
    for (int k = 0; k < KSEL - 1; ++k) {
      const unsigned loA = umn(m[k], tA);
      tA = umx(m[k], tA);
      const unsigned loB = umn(loA, tB);
      tB = umx(loA, tB);
      m[k] = loB;
    }
    m[KSEL - 1] = umn(m[KSEL - 1], umn(tA, tB));
  }

#pragma unroll
  for (int k = 0; k < KSEL; ++k) cand[seg][pt][k] = m[k];
  __syncthreads();

  // One thread per point merges the NSEG sorted partial lists (branchless).
  if (tid < 64) {
    unsigned mm[KSEL];
#pragma unroll
    for (int k = 0; k < KSEL; ++k) mm[k] = cand[0][tid][k];
    for (int s = 1; s < NSEG; ++s) {
#pragma unroll
      for (int k = 0; k < KSEL; ++k) {
        unsigned t = cand[s][tid][k];
#pragma unroll
        for (int q = 0; q < KSEL - 1; ++q) {
          const unsigned lo = umn(mm[q], t);
          t = umx(mm[q], t);
          mm[q] = lo;
        }
        mm[KSEL - 1] = umn(mm[KSEL - 1], t);
      }
    }
    // drop the smallest (self-distance 0), mean of remaining 5
    float s5 = 0.f;
#pragma unroll
    for (int k = 1; k < KSEL; ++k) s5 += __uint_as_float(mm[k]);
    value[b * NPTS + tile * 64 + tid] = s5 * 0.2f;
  }
}

// ---------------------------------------------------------------------------
// Kernel 2: per-batch mean / unbiased std / threshold / masked mean * weight,
// then atomicAdd of loss*(1/BATCH) into out (zeroed by kernel 1).
// grid = 8 blocks, block = 256 threads.
// ---------------------------------------------------------------------------
__global__ __launch_bounds__(256) void stats_kernel(const float* __restrict__ value,
                                                    const float* __restrict__ weights,
                                                    float* __restrict__ out) {
  __shared__ float red[256];
  const int b   = blockIdx.x;
  const int tid = threadIdx.x;
  const float* __restrict__ v = value + b * NPTS;

  // pass 1: mean
  float s = 0.f;
  for (int j = tid; j < NPTS; j += 256) s += v[j];
  red[tid] = s;
  __syncthreads();
  for (int off = 128; off > 0; off >>= 1) {
    if (tid < off) red[tid] += red[tid + off];
    __syncthreads();
  }
  const float mean = red[0] * (1.0f / NPTS);
  __syncthreads();

  // pass 2: unbiased std
  float s2 = 0.f;
  for (int j = tid; j < NPTS; j += 256) {
    const float d = v[j] - mean;
    s2 += d * d;
  }
  red[tid] = s2;
  __syncthreads();
  for (int off = 128; off > 0; off >>= 1) {
    if (tid < off) red[tid] += red[tid + off];
    __syncthreads();
  }
  const float thr = mean + ALPHA * sqrtf(red[0] * (1.0f / (NPTS - 1)));
  __syncthreads();

  // pass 3: masked sum (strict >)
  float s3 = 0.f;
  for (int j = tid; j < NPTS; j += 256) {
    const float vv = v[j];
    if (vv > thr) s3 += vv;
  }
  red[tid] = s3;
  __syncthreads();
  for (int off = 128; off > 0; off >>= 1) {
    if (tid < off) red[tid] += red[tid + off];
    __syncthreads();
  }
  if (tid == 0) {
    atomicAdd(out, red[0] * (1.0f / NPTS) * weights[b] * (1.0f / BATCH));
  }
}

extern "C" void kernel_launch(void* const* d_in, const int* in_sizes, int n_in,
                              void* d_out, int out_size, void* d_ws, size_t ws_size,
                              hipStream_t stream) {
  const float* pc      = (const float*)d_in[0];   // [8,4096,3] f32
  const float* weights = (const float*)d_in[1];   // [8] f32
  float* out   = (float*)d_out;                   // scalar f32
  float* value = (float*)d_ws;                    // [8*4096] f32

  knn_value_kernel<<<dim3(BATCH * (NPTS / 64)), dim3(512), 0, stream>>>(pc, value, out);
  stats_kernel<<<dim3(BATCH), dim3(256), 0, stream>>>(value, weights, out);
}

// Round 4
// 113.392 us; speedup vs baseline: 1.4386x; 1.0175x over previous
//
#include <hip/hip_runtime.h>

#define BATCH 8
#define NPTS 4096
#define KSEL 6          // K_NN + 1
#define ALPHA 1.05f
#define NSEG 8          // candidate-scan split per point

// Non-negative IEEE floats order identically to their uint bit patterns.
// R3 post-mortem: `a<b?a:b` on uint lowered to v_cmp+v_cndmask (2 insts).
// Force single VOP3 3-operand min3/med3/max3 via inline asm: the fused
// 2-candidate insert needs exactly {min3, med3, max3} of each triple.
static __device__ __forceinline__ unsigned min3u(unsigned a, unsigned b, unsigned c) {
  unsigned d;
  asm("v_min3_u32 %0, %1, %2, %3" : "=v"(d) : "v"(a), "v"(b), "v"(c));
  return d;
}
static __device__ __forceinline__ unsigned med3u(unsigned a, unsigned b, unsigned c) {
  unsigned d;
  asm("v_med3_u32 %0, %1, %2, %3" : "=v"(d) : "v"(a), "v"(b), "v"(c));
  return d;
}
static __device__ __forceinline__ unsigned max3u(unsigned a, unsigned b, unsigned c) {
  unsigned d;
  asm("v_max3_u32 %0, %1, %2, %3" : "=v"(d) : "v"(a), "v"(b), "v"(c));
  return d;
}
static __device__ __forceinline__ unsigned umn(unsigned a, unsigned b) { return a < b ? a : b; }
static __device__ __forceinline__ unsigned umx(unsigned a, unsigned b) { return a > b ? a : b; }

#define FINF 0x7F800000u   // +inf bit pattern

// ---------------------------------------------------------------------------
// Kernel 1: per-point mean 5-NN squared distance.
// grid = BATCH * (NPTS/64) = 512 blocks, block = 512 threads (8 waves).
// Wave w (seg = tid>>6) scans candidate segment [seg*512, (seg+1)*512) for all
// 64 points of the block; seg is wave-uniform -> candidate loads are scalar.
// Selection: branchless sorted-insert of 2 candidates/iter. Per level the
// triple {m[k], tA, tB} splits into min3 (stays) and {med3, max3} (propagate);
// multiset-equivalent to sequential insert of A then B (verified absmax 0.0
// in R2/R3 with the 4-op min/max formulation).
// ---------------------------------------------------------------------------
__global__ __launch_bounds__(512) void knn_value_kernel(const float* __restrict__ pc,
                                                        float* __restrict__ value,
                                                        float* __restrict__ out) {
  __shared__ unsigned cand[NSEG][64][KSEL];

  const int tid = threadIdx.x;
  const int pt  = tid & 63;
  const int seg = __builtin_amdgcn_readfirstlane(tid >> 6);  // wave-uniform
  const int b    = blockIdx.x >> 6;
  const int tile = blockIdx.x & 63;
  const int i    = tile * 64 + pt;

  if (blockIdx.x == 0 && tid == 0) out[0] = 0.0f;  // stats kernel accumulates

  const float* __restrict__ base = pc + (size_t)b * (NPTS * 3);
  const float xi = base[i * 3 + 0];
  const float yi = base[i * 3 + 1];
  const float zi = base[i * 3 + 2];

  unsigned m[KSEL];
#pragma unroll
  for (int k = 0; k < KSEL; ++k) m[k] = FINF;

  const float* __restrict__ cbase = base + seg * (NPTS / NSEG) * 3;
#pragma unroll 4
  for (int jj = 0; jj < NPTS / NSEG; jj += 2) {
    // two wave-uniform candidates -> scalar loads
    const float cxA = cbase[jj * 3 + 0];
    const float cyA = cbase[jj * 3 + 1];
    const float czA = cbase[jj * 3 + 2];
    const float cxB = cbase[jj * 3 + 3];
    const float cyB = cbase[jj * 3 + 4];
    const float czB = cbase[jj * 3 + 5];

    const float dxA = xi - cxA, dyA = yi - cyA, dzA = zi - czA;
    const float dxB = xi - cxB, dyB = yi - cyB, dzB = zi - czB;
    float dA = dxA * dxA;
    float dB = dxB * dxB;
    dA = fmaf(dyA, dyA, dA);
    dB = fmaf(dyB, dyB, dB);
    dA = fmaf(dzA, dzA, dA);
    dB = fmaf(dzB, dzB, dB);

    unsigned tA = __float_as_uint(dA);
    unsigned tB = __float_as_uint(dB);
#pragma unroll
    for (int k = 0; k < KSEL - 1; ++k) {
      const unsigned mk = m[k];
      m[k] = min3u(mk, tA, tB);               // smallest of triple stays
      const unsigned nA = med3u(mk, tA, tB);  // two larger propagate
      const unsigned nB = max3u(mk, tA, tB);
      tA = nA;
      tB = nB;
    }
    m[KSEL - 1] = min3u(m[KSEL - 1], tA, tB);
  }

#pragma unroll
  for (int k = 0; k < KSEL; ++k) cand[seg][pt][k] = m[k];
  __syncthreads();

  // One thread per point merges the NSEG sorted partial lists (branchless).
  if (tid < 64) {
    unsigned mm[KSEL];
#pragma unroll
    for (int k = 0; k < KSEL; ++k) mm[k] = cand[0][tid][k];
    for (int s = 1; s < NSEG; ++s) {
#pragma unroll
      for (int k = 0; k < KSEL; ++k) {
        unsigned t = cand[s][tid][k];
#pragma unroll
        for (int q = 0; q < KSEL - 1; ++q) {
          const unsigned lo = umn(mm[q], t);
          t = umx(mm[q], t);
          mm[q] = lo;
        }
        mm[KSEL - 1] = umn(mm[KSEL - 1], t);
      }
    }
    // drop the smallest (self-distance 0), mean of remaining 5
    float s5 = 0.f;
#pragma unroll
    for (int k = 1; k < KSEL; ++k) s5 += __uint_as_float(mm[k]);
    value[b * NPTS + tile * 64 + tid] = s5 * 0.2f;
  }
}

// ---------------------------------------------------------------------------
// Kernel 2: per-batch mean / unbiased std / threshold / masked mean * weight,
// then atomicAdd of loss*(1/BATCH) into out (zeroed by kernel 1).
// grid = 8 blocks, block = 256 threads.
// ---------------------------------------------------------------------------
__global__ __launch_bounds__(256) void stats_kernel(const float* __restrict__ value,
                                                    const float* __restrict__ weights,
                                                    float* __restrict__ out) {
  __shared__ float red[256];
  const int b   = blockIdx.x;
  const int tid = threadIdx.x;
  const float* __restrict__ v = value + b * NPTS;

  // pass 1: mean
  float s = 0.f;
  for (int j = tid; j < NPTS; j += 256) s += v[j];
  red[tid] = s;
  __syncthreads();
  for (int off = 128; off > 0; off >>= 1) {
    if (tid < off) red[tid] += red[tid + off];
    __syncthreads();
  }
  const float mean = red[0] * (1.0f / NPTS);
  __syncthreads();

  // pass 2: unbiased std
  float s2 = 0.f;
  for (int j = tid; j < NPTS; j += 256) {
    const float d = v[j] - mean;
    s2 += d * d;
  }
  red[tid] = s2;
  __syncthreads();
  for (int off = 128; off > 0; off >>= 1) {
    if (tid < off) red[tid] += red[tid + off];
    __syncthreads();
  }
  const float thr = mean + ALPHA * sqrtf(red[0] * (1.0f / (NPTS - 1)));
  __syncthreads();

  // pass 3: masked sum (strict >)
  float s3 = 0.f;
  for (int j = tid; j < NPTS; j += 256) {
    const float vv = v[j];
    if (vv > thr) s3 += vv;
  }
  red[tid] = s3;
  __syncthreads();
  for (int off = 128; off > 0; off >>= 1) {
    if (tid < off) red[tid] += red[tid + off];
    __syncthreads();
  }
  if (tid == 0) {
    atomicAdd(out, red[0] * (1.0f / NPTS) * weights[b] * (1.0f / BATCH));
  }
}

extern "C" void kernel_launch(void* const* d_in, const int* in_sizes, int n_in,
                              void* d_out, int out_size, void* d_ws, size_t ws_size,
                              hipStream_t stream) {
  const float* pc      = (const float*)d_in[0];   // [8,4096,3] f32
  const float* weights = (const float*)d_in[1];   // [8] f32
  float* out   = (float*)d_out;                   // scalar f32
  float* value = (float*)d_ws;                    // [8*4096] f32

  knn_value_kernel<<<dim3(BATCH * (NPTS / 64)), dim3(512), 0, stream>>>(pc, value, out);
  stats_kernel<<<dim3(BATCH), dim3(256), 0, stream>>>(value, weights, out);
}

// Round 5
// 103.443 us; speedup vs baseline: 1.5770x; 1.0962x over previous
//
#include <hip/hip_runtime.h>

#define BATCH 8
#define NPTS 4096
#define KSEL 6          // K_NN + 1
#define ALPHA 1.05f
#define NSEG 16         // candidate-scan split per point (one wave each)
#define SEGLEN (NPTS / NSEG)   // 256
#define TPB (NSEG * 64)        // 1024 threads

// Non-negative IEEE floats order identically to their uint bit patterns.
// Fused 2-candidate sorted-insert: per level {m[k],tA,tB} -> min3 stays,
// {med3,max3} propagate. Bit-identical to sequential insert (absmax 0.0 R2-R4).
static __device__ __forceinline__ unsigned min3u(unsigned a, unsigned b, unsigned c) {
  unsigned d;
  asm("v_min3_u32 %0, %1, %2, %3" : "=v"(d) : "v"(a), "v"(b), "v"(c));
  return d;
}
static __device__ __forceinline__ unsigned med3u(unsigned a, unsigned b, unsigned c) {
  unsigned d;
  asm("v_med3_u32 %0, %1, %2, %3" : "=v"(d) : "v"(a), "v"(b), "v"(c));
  return d;
}
static __device__ __forceinline__ unsigned max3u(unsigned a, unsigned b, unsigned c) {
  unsigned d;
  asm("v_max3_u32 %0, %1, %2, %3" : "=v"(d) : "v"(a), "v"(b), "v"(c));
  return d;
}
static __device__ __forceinline__ unsigned umn(unsigned a, unsigned b) { return a < b ? a : b; }
static __device__ __forceinline__ unsigned umx(unsigned a, unsigned b) { return a > b ? a : b; }

#define FINF 0x7F800000u   // +inf bit pattern

// Fused branchless insert of two candidates into sorted m[0..5].
static __device__ __forceinline__ void insert2(unsigned m[KSEL], unsigned tA, unsigned tB) {
#pragma unroll
  for (int k = 0; k < KSEL - 1; ++k) {
    const unsigned mk = m[k];
    m[k] = min3u(mk, tA, tB);
    const unsigned nA = med3u(mk, tA, tB);
    const unsigned nB = max3u(mk, tA, tB);
    tA = nA;
    tB = nB;
  }
  m[KSEL - 1] = min3u(m[KSEL - 1], tA, tB);
}

// ---------------------------------------------------------------------------
// Kernel 1: per-point mean 5-NN squared distance.
// grid = BATCH * (NPTS/64) = 512 blocks, block = 1024 threads (16 waves).
// Candidates staged once into LDS in SoA form; inner loop reads 4 candidates
// per iteration via 3 ds_read_b128 at wave-uniform addresses (broadcast,
// immediate offsets -> no per-iter address VALU). Wave w scans segment
// [w*256, (w+1)*256); 16 partial top-6 lists tree-merged in LDS (the stage
// buffer is reused for the lists -> 48 KB total, 2 blocks/CU, 32 waves/CU).
// ---------------------------------------------------------------------------
__global__ __launch_bounds__(TPB) void knn_value_kernel(const float* __restrict__ pc,
                                                        float* __restrict__ value,
                                                        float* __restrict__ out) {
  __shared__ union __align__(16) {
    struct { float xs[NPTS]; float ys[NPTS]; float zs[NPTS]; } s;  // 48 KB
    unsigned cand[NSEG][64][KSEL];                                 // 24 KB
  } sh;

  const int tid = threadIdx.x;
  const int pt  = tid & 63;
  const int seg = __builtin_amdgcn_readfirstlane(tid >> 6);  // wave-uniform
  const int b    = blockIdx.x >> 6;
  const int tile = blockIdx.x & 63;
  const int i    = tile * 64 + pt;

  if (blockIdx.x == 0 && tid == 0) out[0] = 0.0f;  // stats kernel accumulates

  const float* __restrict__ base = pc + (size_t)b * (NPTS * 3);

  // Stage batch point cloud into LDS (SoA). 4 points per thread.
#pragma unroll
  for (int p = 0; p < NPTS / TPB; ++p) {
    const int idx = tid + p * TPB;
    sh.s.xs[idx] = base[idx * 3 + 0];
    sh.s.ys[idx] = base[idx * 3 + 1];
    sh.s.zs[idx] = base[idx * 3 + 2];
  }
  __syncthreads();

  const float xi = sh.s.xs[i];
  const float yi = sh.s.ys[i];
  const float zi = sh.s.zs[i];

  unsigned m[KSEL];
#pragma unroll
  for (int k = 0; k < KSEL; ++k) m[k] = FINF;

  const int j0 = seg * SEGLEN;
#pragma unroll 4
  for (int jj = 0; jj < SEGLEN; jj += 4) {
    // 4 wave-uniform candidates: 3x ds_read_b128 broadcast
    const float4 cx = *(const float4*)&sh.s.xs[j0 + jj];
    const float4 cy = *(const float4*)&sh.s.ys[j0 + jj];
    const float4 cz = *(const float4*)&sh.s.zs[j0 + jj];

    const float dxA = xi - cx.x, dyA = yi - cy.x, dzA = zi - cz.x;
    const float dxB = xi - cx.y, dyB = yi - cy.y, dzB = zi - cz.y;
    const float dxC = xi - cx.z, dyC = yi - cy.z, dzC = zi - cz.z;
    const float dxD = xi - cx.w, dyD = yi - cy.w, dzD = zi - cz.w;
    float dA = dxA * dxA, dB = dxB * dxB, dC = dxC * dxC, dD = dxD * dxD;
    dA = fmaf(dyA, dyA, dA);
    dB = fmaf(dyB, dyB, dB);
    dC = fmaf(dyC, dyC, dC);
    dD = fmaf(dyD, dyD, dD);
    dA = fmaf(dzA, dzA, dA);
    dB = fmaf(dzB, dzB, dB);
    dC = fmaf(dzC, dzC, dC);
    dD = fmaf(dzD, dzD, dD);

    insert2(m, __float_as_uint(dA), __float_as_uint(dB));
    insert2(m, __float_as_uint(dC), __float_as_uint(dD));
  }
  __syncthreads();  // everyone done reading the stage buffer

#pragma unroll
  for (int k = 0; k < KSEL; ++k) sh.cand[seg][pt][k] = m[k];
  __syncthreads();

  // Tree-merge the 16 sorted lists per point: 8,4,2,1 pairwise merges.
  for (int st = 1; st < NSEG; st <<= 1) {
    const int pairs = NSEG / (2 * st);
    if (tid < pairs * 64) {
      const int q = tid >> 6;
      const int p = tid & 63;
      unsigned* A = &sh.cand[2 * st * q][p][0];
      const unsigned* B = &sh.cand[2 * st * q + st][p][0];
      unsigned mm[KSEL];
#pragma unroll
      for (int k = 0; k < KSEL; ++k) mm[k] = A[k];
#pragma unroll
      for (int k = 0; k < KSEL; ++k) {
        unsigned t = B[k];
#pragma unroll
        for (int u = 0; u < KSEL - 1; ++u) {
          const unsigned lo = umn(mm[u], t);
          t = umx(mm[u], t);
          mm[u] = lo;
        }
        mm[KSEL - 1] = umn(mm[KSEL - 1], t);
      }
#pragma unroll
      for (int k = 0; k < KSEL; ++k) A[k] = mm[k];
    }
    __syncthreads();
  }

  // drop the smallest (self-distance 0), mean of remaining 5
  if (tid < 64) {
    float s5 = 0.f;
#pragma unroll
    for (int k = 1; k < KSEL; ++k) s5 += __uint_as_float(sh.cand[0][tid][k]);
    value[b * NPTS + tile * 64 + tid] = s5 * 0.2f;
  }
}

// ---------------------------------------------------------------------------
// Kernel 2: per-batch mean / unbiased std / threshold / masked mean * weight,
// then atomicAdd of loss*(1/BATCH) into out (zeroed by kernel 1).
// grid = 8 blocks, block = 256 threads.
// ---------------------------------------------------------------------------
__global__ __launch_bounds__(256) void stats_kernel(const float* __restrict__ value,
                                                    const float* __restrict__ weights,
                                                    float* __restrict__ out) {
  __shared__ float red[256];
  const int b   = blockIdx.x;
  const int tid = threadIdx.x;
  const float* __restrict__ v = value + b * NPTS;

  // pass 1: mean
  float s = 0.f;
  for (int j = tid; j < NPTS; j += 256) s += v[j];
  red[tid] = s;
  __syncthreads();
  for (int off = 128; off > 0; off >>= 1) {
    if (tid < off) red[tid] += red[tid + off];
    __syncthreads();
  }
  const float mean = red[0] * (1.0f / NPTS);
  __syncthreads();

  // pass 2: unbiased std
  float s2 = 0.f;
  for (int j = tid; j < NPTS; j += 256) {
    const float d = v[j] - mean;
    s2 += d * d;
  }
  red[tid] = s2;
  __syncthreads();
  for (int off = 128; off > 0; off >>= 1) {
    if (tid < off) red[tid] += red[tid + off];
    __syncthreads();
  }
  const float thr = mean + ALPHA * sqrtf(red[0] * (1.0f / (NPTS - 1)));
  __syncthreads();

  // pass 3: masked sum (strict >)
  float s3 = 0.f;
  for (int j = tid; j < NPTS; j += 256) {
    const float vv = v[j];
    if (vv > thr) s3 += vv;
  }
  red[tid] = s3;
  __syncthreads();
  for (int off = 128; off > 0; off >>= 1) {
    if (tid < off) red[tid] += red[tid + off];
    __syncthreads();
  }
  if (tid == 0) {
    atomicAdd(out, red[0] * (1.0f / NPTS) * weights[b] * (1.0f / BATCH));
  }
}

extern "C" void kernel_launch(void* const* d_in, const int* in_sizes, int n_in,
                              void* d_out, int out_size, void* d_ws, size_t ws_size,
                              hipStream_t stream) {
  const float* pc      = (const float*)d_in[0];   // [8,4096,3] f32
  const float* weights = (const float*)d_in[1];   // [8] f32
  float* out   = (float*)d_out;                   // scalar f32
  float* value = (float*)d_ws;                    // [8*4096] f32

  knn_value_kernel<<<dim3(BATCH * (NPTS / 64)), dim3(TPB), 0, stream>>>(pc, value, out);
  stats_kernel<<<dim3(BATCH), dim3(256), 0, stream>>>(value, weights, out);
}